// Round 5
// baseline (107.708 us; speedup 1.0000x reference)
//
#include <hip/hip_runtime.h>

// PhiRestraint: masked sum over (B,P) of cubic-spline(angle at x_CB between
// (x_CA - x_CB) and (y_CB - x_CB)), interval by searchsorted(cutoffs, phi).
// B=8, L=512, P=80000, K=16 knots -> 15 intervals.
//
// R4: lean single-pass version. R1 (global coords) == R2 (LDS coords) within
// noise -> coord path is not the bottleneck; kernel is bound by the
// compulsory random coeff gather (L3 is swept by the harness's 268MB ws
// poison each iteration). So: no LDS staging, no __syncthreads, exactly one
// item per thread (2500x256 == 640000), wave-level reduce only (lane0 writes
// one of 10000 wave partials). Item index = p*8+b keeps the 8 batches of a
// pair in consecutive lanes so their 16B coeff gathers merge into the same
// 240B row (~3-4 lines per pair-group).

namespace {
constexpr int BATCH = 8;
constexpr int SEQL  = 512;
constexpr int NPAIR = 80000;
constexpr int NKNOT = 16;
constexpr int NINT  = 15;
constexpr int BLOCK = 256;
constexpr int TOTAL = BATCH * NPAIR;   // 640000
constexpr int NBLK  = TOTAL / BLOCK;   // 2500 exactly, no tail
constexpr int NWAVE = TOTAL / 64;      // 10000 wave partials (40 KB in ws)
constexpr int RB    = 1024;            // reduce-kernel block size
}

__global__ __launch_bounds__(BLOCK) void phi_main_kernel(
    const float* __restrict__ CA, const float* __restrict__ CB,
    const float* __restrict__ coeff, const float* __restrict__ cutoffs,
    const int* __restrict__ x_idx, const int* __restrict__ y_idx,
    float* __restrict__ partial)
{
    const int tid = blockIdx.x * BLOCK + threadIdx.x;  // < TOTAL exactly
    const int p = tid >> 3;
    const int b = tid & 7;

    // 8 consecutive lanes share p -> one 32B segment per 8 lanes
    const int xi = x_idx[p];
    const int yi = y_idx[p];

    const float* pxa = CA + (size_t)(b * SEQL + xi) * 3;
    const float* pxb = CB + (size_t)(b * SEQL + xi) * 3;
    const float* pyb = CB + (size_t)(b * SEQL + yi) * 3;

    const float xax = pxa[0], xay = pxa[1], xaz = pxa[2];
    const float xbx = pxb[0], xby = pxb[1], xbz = pxb[2];
    const float ybx = pyb[0], yby = pyb[1], ybz = pyb[2];

    // x = x_CA - x_CB ; y = y_CB - x_CB   (exact f32, same as reference)
    const float xx = xax - xbx, xy = xay - xby, xz = xaz - xbz;
    const float yx = ybx - xbx, yy = yby - xby, yz = ybz - xbz;

    const float nx = sqrtf(xx * xx + xy * xy + xz * xz);
    const float ny = sqrtf(yx * yx + yy * yy + yz * yz);

    const float eps = 1e-6f;
    const bool valid = (nx > eps) && (ny > eps);
    const float denom = valid ? nx * ny : 1.0f;
    const float c = (xx * yx + xy * yy + xz * yz) / denom;
    const bool good = (1.0f - c * c) > eps;
    const bool m = valid && good;

    float acc = 0.0f;
    if (m) {
        const float clip_hi = 1.0f - 1e-7f;  // f32(1-1e-7) == 0x3F7FFFFE
        const float cl = fminf(fmaxf(c, -clip_hi), clip_hi);
        const float phi = acosf(cl);

        // searchsorted(cutoffs, phi, 'left') = #cutoffs strictly < phi.
        // Track the largest cutoff < phi (avoids a dependent reload).
        // phi in (0,pi]; cutoffs span [-0.39, pi+0.39] -> cnt in [1,15].
        int cnt = 0;
        float low = cutoffs[0];
        #pragma unroll
        for (int t = 0; t < NKNOT; ++t) {
            const float ck = cutoffs[t];  // wave-uniform -> s_load
            const bool lt = ck < phi;
            cnt += lt ? 1 : 0;
            low = lt ? ck : low;
        }
        int idx = cnt - 1;
        idx = idx < 0 ? 0 : (idx > NINT - 1 ? NINT - 1 : idx);

        const float dx = phi - low;

        // 16B gather of the selected interval's 4 poly coeffs (compulsory
        // random traffic; 8 same-row lanes merge in the coalescer)
        const float4 cf = *reinterpret_cast<const float4*>(
            coeff + ((size_t)(xi * SEQL + yi) * NINT + idx) * 4);

        // c3 + dx*(c2 + dx*(c1 + dx*c0))
        acc = cf.w + dx * (cf.z + dx * (cf.y + dx * cf.x));
    }

    // wave-level reduce only: no LDS, no __syncthreads in the hot kernel
    #pragma unroll
    for (int o = 32; o > 0; o >>= 1) acc += __shfl_down(acc, o, 64);
    if ((threadIdx.x & 63) == 0) partial[tid >> 6] = acc;
}

__global__ __launch_bounds__(RB) void phi_reduce_kernel(
    const float* __restrict__ partial, float* __restrict__ out)
{
    float v = 0.0f;
    for (int i = threadIdx.x; i < NWAVE; i += RB) v += partial[i];  // 40 KB coalesced
    #pragma unroll
    for (int o = 32; o > 0; o >>= 1) v += __shfl_down(v, o, 64);

    __shared__ float red[RB / 64];
    const int wave = threadIdx.x >> 6;
    const int lane = threadIdx.x & 63;
    if (lane == 0) red[wave] = v;
    __syncthreads();
    if (wave == 0) {
        v = (lane < RB / 64) ? red[lane] : 0.0f;
        #pragma unroll
        for (int o = 8; o > 0; o >>= 1) v += __shfl_down(v, o, 64);
        if (lane == 0) out[0] = v;
    }
}

extern "C" void kernel_launch(void* const* d_in, const int* in_sizes, int n_in,
                              void* d_out, int out_size, void* d_ws, size_t ws_size,
                              hipStream_t stream) {
    const float* CA      = (const float*)d_in[0];
    const float* CB      = (const float*)d_in[1];
    const float* coeff   = (const float*)d_in[2];
    const float* cutoffs = (const float*)d_in[3];
    const int*   x_idx   = (const int*)d_in[4];
    const int*   y_idx   = (const int*)d_in[5];
    float* out = (float*)d_out;
    float* partial = (float*)d_ws;  // NWAVE floats = 40 KB scratch

    phi_main_kernel<<<NBLK, BLOCK, 0, stream>>>(CA, CB, coeff, cutoffs,
                                                x_idx, y_idx, partial);
    phi_reduce_kernel<<<1, RB, 0, stream>>>(partial, out);
}